// Round 11
// baseline (476.095 us; speedup 1.0000x reference)
//
#include <hip/hip_runtime.h>

#define NN 50000
#define NE 800000
#define NSLICE 6250   // NN/8: nodes per XCD slice

typedef short s8v  __attribute__((ext_vector_type(8)));   // 8 bf16 (4 VGPRs)
typedef float f4v  __attribute__((ext_vector_type(4)));   // MFMA acc

__device__ __forceinline__ unsigned f2bf(float f) {       // RNE pack
    unsigned u = __float_as_uint(f);
    return (u + 0x7fffu + ((u >> 16) & 1u)) >> 16;
}
__device__ __forceinline__ float bf2f_lo(unsigned u) { return __uint_as_float(u << 16); }
__device__ __forceinline__ float bf2f_hi(unsigned u) { return __uint_as_float(u & 0xffff0000u); }

// ================= fused prep: cast x -> bf16 | transpose W -> bf16 | deg=0 =================
__global__ __launch_bounds__(256) void k_prep(const float4* __restrict__ x4, uint2* __restrict__ xb,
                                              const float* __restrict__ W1, const float* __restrict__ W2,
                                              const float* __restrict__ Wmu, const float* __restrict__ Wlv,
                                              unsigned short* __restrict__ Wt, int* __restrict__ deg) {
    int b = blockIdx.x;
    if (b < 6250) {
        int i = b * 256 + threadIdx.x;
        if (i >= NN * 32) return;
        float4 v = x4[i];
        uint2 p;
        p.x = (f2bf(v.y) << 16) | f2bf(v.x);
        p.y = (f2bf(v.w) << 16) | f2bf(v.z);
        xb[i] = p;
    } else if (b < 6442) {
        int idx = (b - 6250) * 256 + threadIdx.x;
        if (idx >= 3 * 16384) return;
        int m = idx >> 14, i = idx & 16383;
        int n = i & 127, k = i >> 7;
        float v;
        if (m == 0)      v = W1[k * 128 + n];
        else if (m == 1) v = W2[k * 128 + n];
        else             v = (n < 64) ? Wmu[k * 64 + n] : Wlv[k * 64 + (n - 64)];
        Wt[m * 16384 + n * 128 + k] = (unsigned short)f2bf(v);
    } else {
        int i = (b - 6442) * 256 + threadIdx.x;
        if (i < NN) deg[i] = 0;
    }
}

// XCD-sliced degree count (block b&7 -> node slice, atomic targets stay in one L2)
__global__ __launch_bounds__(256) void k_deg_count(const int* __restrict__ dst, int* __restrict__ deg) {
    int xcd = blockIdx.x & 7;
    int e = (blockIdx.x >> 3) * 256 + threadIdx.x;
    if (e >= NE) return;
    int d = dst[e];
    if (d / NSLICE == xcd) atomicAdd(&deg[d], 1);
}

// ================= single-dispatch scan (dinv fused) =================
__global__ __launch_bounds__(1024) void k_scan(int* __restrict__ deg, float* __restrict__ dinv,
                                               int* __restrict__ off) {
    __shared__ int ps[1024];
    int tid = threadIdx.x;
    const int CH = (NN + 1023) / 1024;   // 49
    int base = tid * CH;
    int sum = 0;
    for (int k = 0; k < CH; ++k) {
        int i = base + k;
        if (i < NN) {
            int v = deg[i];
            sum += v;
            dinv[i] = rsqrtf((float)(v + 1));   // +1 = self loop
        }
    }
    ps[tid] = sum;
    __syncthreads();
    for (int d = 1; d < 1024; d <<= 1) {
        int t = (tid >= d) ? ps[tid - d] : 0;
        __syncthreads();
        ps[tid] += t;
        __syncthreads();
    }
    int run = (tid > 0) ? ps[tid - 1] : 0;   // exclusive prefix of this chunk
    for (int k = 0; k < CH; ++k) {
        int i = base + k;
        if (i < NN) {
            int v = deg[i];
            off[i] = run;
            deg[i] = run;   // cursor
            run += v;
        }
    }
    if (tid == 0) off[NN] = NE;
}

// XCD-sliced CSR fill (slice's ~800KB epair region stays in its XCD's L2)
__global__ __launch_bounds__(256) void k_fill(const int* __restrict__ src, const int* __restrict__ dst,
                                              const float* __restrict__ dinv,
                                              int* __restrict__ cursor, int2* __restrict__ epair) {
    int xcd = blockIdx.x & 7;
    int e = (blockIdx.x >> 3) * 256 + threadIdx.x;
    if (e >= NE) return;
    int d = dst[e];
    if (d / NSLICE != xcd) return;
    int s = src[e];
    int p = atomicAdd(&cursor[d], 1);
    epair[p] = make_int2(s, __float_as_int(dinv[s] * dinv[d]));
}

// ================= bf16 MFMA GEMM: Cb[N,128] = Xb[N,128] @ Wt^T =================
__global__ __launch_bounds__(256) void k_gemm(const unsigned short* __restrict__ Xb,
                                              const unsigned short* __restrict__ Wt,
                                              unsigned short* __restrict__ Cb, int N) {
    int wave = threadIdx.x >> 6, lane = threadIdx.x & 63;
    int quad = lane >> 4, l16 = lane & 15;
    int row0 = blockIdx.x * 64 + wave * 16;
    int arow = row0 + l16;
    int arc  = arow < N ? arow : N - 1;          // clamp (stores guarded)

    const s8v* xp = (const s8v*)(Xb + (size_t)arc * 128);
    s8v a0 = xp[quad], a1 = xp[4 + quad], a2 = xp[8 + quad], a3 = xp[12 + quad];

    f4v acc[8];
#pragma unroll
    for (int c = 0; c < 8; ++c) acc[c] = (f4v)0.f;

#pragma unroll
    for (int c = 0; c < 8; ++c) {
        const s8v* wp = (const s8v*)(Wt + (size_t)(c * 16 + l16) * 128);
        acc[c] = __builtin_amdgcn_mfma_f32_16x16x32_bf16(a0, wp[quad],      acc[c], 0, 0, 0);
        acc[c] = __builtin_amdgcn_mfma_f32_16x16x32_bf16(a1, wp[4 + quad],  acc[c], 0, 0, 0);
        acc[c] = __builtin_amdgcn_mfma_f32_16x16x32_bf16(a2, wp[8 + quad],  acc[c], 0, 0, 0);
        acc[c] = __builtin_amdgcn_mfma_f32_16x16x32_bf16(a3, wp[12 + quad], acc[c], 0, 0, 0);
    }

#pragma unroll
    for (int c = 0; c < 8; ++c) {
#pragma unroll
        for (int r = 0; r < 4; ++r) {
            int ro = row0 + quad * 4 + r;
            if (ro < N) Cb[(size_t)ro * 128 + c * 16 + l16] = (unsigned short)f2bf(acc[c][r]);
        }
    }
}

// ================= final: [mu|lv] = Xb @ Wt^T + bias, fp32 packed out =================
__global__ __launch_bounds__(256) void k_final(const unsigned short* __restrict__ Xb,
                                               const unsigned short* __restrict__ Wt,
                                               const float* __restrict__ bmu, const float* __restrict__ blv,
                                               float* __restrict__ out, int N) {
    int wave = threadIdx.x >> 6, lane = threadIdx.x & 63;
    int quad = lane >> 4, l16 = lane & 15;
    int row0 = blockIdx.x * 64 + wave * 16;
    int arow = row0 + l16;
    int arc  = arow < N ? arow : N - 1;

    const s8v* xp = (const s8v*)(Xb + (size_t)arc * 128);
    s8v a0 = xp[quad], a1 = xp[4 + quad], a2 = xp[8 + quad], a3 = xp[12 + quad];

    f4v acc[8];
#pragma unroll
    for (int c = 0; c < 8; ++c) acc[c] = (f4v)0.f;

#pragma unroll
    for (int c = 0; c < 8; ++c) {
        const s8v* wp = (const s8v*)(Wt + (size_t)(c * 16 + l16) * 128);
        acc[c] = __builtin_amdgcn_mfma_f32_16x16x32_bf16(a0, wp[quad],      acc[c], 0, 0, 0);
        acc[c] = __builtin_amdgcn_mfma_f32_16x16x32_bf16(a1, wp[4 + quad],  acc[c], 0, 0, 0);
        acc[c] = __builtin_amdgcn_mfma_f32_16x16x32_bf16(a2, wp[8 + quad],  acc[c], 0, 0, 0);
        acc[c] = __builtin_amdgcn_mfma_f32_16x16x32_bf16(a3, wp[12 + quad], acc[c], 0, 0, 0);
    }

#pragma unroll
    for (int c = 0; c < 8; ++c) {
        int col  = c * 16 + l16;
        float bb = (col < 64) ? bmu[col] : blv[col - 64];
#pragma unroll
        for (int r = 0; r < 4; ++r) {
            int ro = row0 + quad * 4 + r;
            if (ro < N) {
                float v = acc[c][r] + bb;
                if (col < 64) out[(size_t)ro * 64 + col] = v;
                else          out[(size_t)NN * 64 + (size_t)ro * 64 + (col - 64)] = v;
            }
        }
    }
}

// ================= gather agg (bf16) + self-loop + bias + relu -> bf16 =================
// 1 wave/node. Lane-group g=lane>>4 handles edge e0+g; lane loads dwordx4 (16B)
// at dword offset q*4 of its group's source row -> ONE instruction fetches 4
// whole rows (1KB). Macro internals are underscore-prefixed: round-10's bug was
// caller args w0..w3 shadowed by macro locals (first 16 edges got uninit weights).
__global__ __launch_bounds__(256) void k_agg(const unsigned short* __restrict__ hb, const int* __restrict__ off,
                                             const int2* __restrict__ epair, const float* __restrict__ dinv,
                                             const float* __restrict__ b, unsigned* __restrict__ outw) {
    int lane = threadIdx.x & 63;
    int g = lane >> 4, q = lane & 15;
    int n = blockIdx.x * 4 + (threadIdx.x >> 6);   // grid = 12500 -> n < 50000
    int o0 = __builtin_amdgcn_readfirstlane(off[n]);
    int o1 = __builtin_amdgcn_readfirstlane(off[n + 1]);

    float al0 = 0.f, al1 = 0.f, al2 = 0.f, al3 = 0.f;
    float ah0 = 0.f, ah1 = 0.f, ah2 = 0.f, ah3 = 0.f;

#define BATCH4_LOAD(e0, uj, wj)                                                          \
    {                                                                                    \
        int _i0 = ((e0) + 0 < o1) ? (e0) + 0 : 0;                                        \
        int _i1 = ((e0) + 1 < o1) ? (e0) + 1 : 0;                                        \
        int _i2 = ((e0) + 2 < o1) ? (e0) + 2 : 0;                                        \
        int _i3 = ((e0) + 3 < o1) ? (e0) + 3 : 0;                                        \
        int _s0 = __builtin_amdgcn_readfirstlane(epair[_i0].x);                          \
        int _s1 = __builtin_amdgcn_readfirstlane(epair[_i1].x);                          \
        int _s2 = __builtin_amdgcn_readfirstlane(epair[_i2].x);                          \
        int _s3 = __builtin_amdgcn_readfirstlane(epair[_i3].x);                          \
        float _w0 = ((e0) + 0 < o1) ? __int_as_float(__builtin_amdgcn_readfirstlane(epair[_i0].y)) : 0.f; \
        float _w1 = ((e0) + 1 < o1) ? __int_as_float(__builtin_amdgcn_readfirstlane(epair[_i1].y)) : 0.f; \
        float _w2 = ((e0) + 2 < o1) ? __int_as_float(__builtin_amdgcn_readfirstlane(epair[_i2].y)) : 0.f; \
        float _w3 = ((e0) + 3 < o1) ? __int_as_float(__builtin_amdgcn_readfirstlane(epair[_i3].y)) : 0.f; \
        int _ss = (g == 0) ? _s0 : (g == 1) ? _s1 : (g == 2) ? _s2 : _s3;                \
        wj = (g == 0) ? _w0 : (g == 1) ? _w1 : (g == 2) ? _w2 : _w3;                     \
        uj = ((const uint4*)(hb + (size_t)_ss * 128))[q];                                \
    }

#define BATCH4_FMA(uj, wj)                                                               \
    {                                                                                    \
        al0 += bf2f_lo(uj.x) * wj; ah0 += bf2f_hi(uj.x) * wj;                            \
        al1 += bf2f_lo(uj.y) * wj; ah1 += bf2f_hi(uj.y) * wj;                            \
        al2 += bf2f_lo(uj.z) * wj; ah2 += bf2f_hi(uj.z) * wj;                            \
        al3 += bf2f_lo(uj.w) * wj; ah3 += bf2f_hi(uj.w) * wj;                            \
    }

    {   // prologue: 24 edges, 6 independent 1KB gathers in flight
        uint4 u0, u1, u2, u3, u4, u5;
        float w0, w1, w2, w3, w4, w5;
        BATCH4_LOAD(o0 + 0,  u0, w0);
        BATCH4_LOAD(o0 + 4,  u1, w1);
        BATCH4_LOAD(o0 + 8,  u2, w2);
        BATCH4_LOAD(o0 + 12, u3, w3);
        BATCH4_LOAD(o0 + 16, u4, w4);
        BATCH4_LOAD(o0 + 20, u5, w5);
        BATCH4_FMA(u0, w0); BATCH4_FMA(u1, w1); BATCH4_FMA(u2, w2);
        BATCH4_FMA(u3, w3); BATCH4_FMA(u4, w4); BATCH4_FMA(u5, w5);
    }

    // epilogue for deg > 24 (P ~ 2%): masked 4-edge batches, 2 in flight
    for (int e0 = o0 + 24; e0 < o1; e0 += 8) {
        uint4 u0, u1; float w0, w1;
        BATCH4_LOAD(e0, u0, w0);
        BATCH4_LOAD(e0 + 4, u1, w1);
        BATCH4_FMA(u0, w0);
        BATCH4_FMA(u1, w1);
    }
#undef BATCH4_LOAD
#undef BATCH4_FMA

    // butterfly-reduce the 4 edge-subgroups (lanes differing in bits 4,5)
    al0 += __shfl_xor(al0, 16, 64); al0 += __shfl_xor(al0, 32, 64);
    ah0 += __shfl_xor(ah0, 16, 64); ah0 += __shfl_xor(ah0, 32, 64);
    al1 += __shfl_xor(al1, 16, 64); al1 += __shfl_xor(al1, 32, 64);
    ah1 += __shfl_xor(ah1, 16, 64); ah1 += __shfl_xor(ah1, 32, 64);
    al2 += __shfl_xor(al2, 16, 64); al2 += __shfl_xor(al2, 32, 64);
    ah2 += __shfl_xor(ah2, 16, 64); ah2 += __shfl_xor(ah2, 32, 64);
    al3 += __shfl_xor(al3, 16, 64); al3 += __shfl_xor(al3, 32, 64);
    ah3 += __shfl_xor(ah3, 16, 64); ah3 += __shfl_xor(ah3, 32, 64);

    if (g == 0) {
        float dn = dinv[n];
        float sn = dn * dn;
        uint4 uh = ((const uint4*)(hb + (size_t)n * 128))[q];
        const float2* b2 = (const float2*)b;
        float2 bb0 = b2[q * 4 + 0], bb1 = b2[q * 4 + 1];
        float2 bb2 = b2[q * 4 + 2], bb3 = b2[q * 4 + 3];
        uint4 o;
        float rx, ry;
        rx = fmaxf(al0 + bf2f_lo(uh.x) * sn + bb0.x, 0.f);
        ry = fmaxf(ah0 + bf2f_hi(uh.x) * sn + bb0.y, 0.f);
        o.x = (f2bf(ry) << 16) | f2bf(rx);
        rx = fmaxf(al1 + bf2f_lo(uh.y) * sn + bb1.x, 0.f);
        ry = fmaxf(ah1 + bf2f_hi(uh.y) * sn + bb1.y, 0.f);
        o.y = (f2bf(ry) << 16) | f2bf(rx);
        rx = fmaxf(al2 + bf2f_lo(uh.z) * sn + bb2.x, 0.f);
        ry = fmaxf(ah2 + bf2f_hi(uh.z) * sn + bb2.y, 0.f);
        o.z = (f2bf(ry) << 16) | f2bf(rx);
        rx = fmaxf(al3 + bf2f_lo(uh.w) * sn + bb3.x, 0.f);
        ry = fmaxf(ah3 + bf2f_hi(uh.w) * sn + bb3.y, 0.f);
        o.w = (f2bf(ry) << 16) | f2bf(rx);
        ((uint4*)(outw + (size_t)n * 64))[q] = o;
    }
}

extern "C" void kernel_launch(void* const* d_in, const int* in_sizes, int n_in,
                              void* d_out, int out_size, void* d_ws, size_t ws_size,
                              hipStream_t stream) {
    const float* x    = (const float*)d_in[0];
    const int*   eidx = (const int*)d_in[1];
    const float* W1   = (const float*)d_in[2];
    const float* b1   = (const float*)d_in[3];
    const float* W2   = (const float*)d_in[4];
    const float* b2   = (const float*)d_in[5];
    const float* Wmu  = (const float*)d_in[6];
    const float* bmu  = (const float*)d_in[7];
    const float* Wlv  = (const float*)d_in[8];
    const float* blv  = (const float*)d_in[9];
    float* out = (float*)d_out;

    const int* src = eidx;        // edge_index[0]
    const int* dst = eidx + NE;   // edge_index[1]

    // workspace layout (4-byte units)
    float*          ws    = (float*)d_ws;
    float*          dinv  = ws;                            // 50048
    int*            deg   = (int*)(ws + 50048);            // 50048 (becomes cursor)
    int*            off   = (int*)(ws + 100096);           // 50048
    int2*           epair = (int2*)(ws + 150400);          // 800000 int2
    unsigned short* Wt    = (unsigned short*)(ws + 1750400);   // 3*16384 bf16
    unsigned short* Xb    = (unsigned short*)(ws + 1775000);   // 6.4M bf16
    unsigned short* Hb    = (unsigned short*)(ws + 4975000);   // 6.4M bf16
    unsigned short* Gb    = (unsigned short*)(ws + 8175000);   // 6.4M bf16

    const int gE8 = ((NE + 255) / 256) * 8;  // 25000 (XCD-sliced passes)
    const int gG  = (NN + 63) / 64;          // 782
    const int gA  = NN / 4;                  // 12500
    const int gP  = 6250 + 192 + 196;        // fused prep grid

    // ---- fused prep: cast x, transpose W, zero deg ----
    k_prep<<<gP, 256, 0, stream>>>((const float4*)x, (uint2*)Xb, W1, W2, Wmu, Wlv, Wt, deg);

    // ---- CSR build + norms ----
    k_deg_count<<<gE8, 256, 0, stream>>>(dst, deg);
    k_scan<<<1, 1024, 0, stream>>>(deg, dinv, off);
    k_fill<<<gE8, 256, 0, stream>>>(src, dst, dinv, deg, epair);

    // ---- conv1: Hb = Xb@W1 ; Gb = relu(agg(Hb) + self + b1) ----
    k_gemm<<<gG, 256, 0, stream>>>(Xb, Wt, Hb, NN);
    k_agg<<<gA, 256, 0, stream>>>(Hb, off, epair, dinv, b1, (unsigned*)Gb);

    // ---- conv2: Hb = Gb@W2 ; Gb = relu(agg(Hb) + self + b2) ----
    k_gemm<<<gG, 256, 0, stream>>>(Gb, Wt + 16384, Hb, NN);
    k_agg<<<gA, 256, 0, stream>>>(Hb, off, epair, dinv, b2, (unsigned*)Gb);

    // ---- final projection ----
    k_final<<<gG, 256, 0, stream>>>(Gb, Wt + 32768, bmu, blv, out, NN);
}

// Round 12
// 322.104 us; speedup vs baseline: 1.4781x; 1.4781x over previous
//
#include <hip/hip_runtime.h>

#define NN 50000
#define NE 800000
#define NSLICE 6250   // NN/8: nodes per XCD slice

typedef short s8v  __attribute__((ext_vector_type(8)));   // 8 bf16 (4 VGPRs)
typedef float f4v  __attribute__((ext_vector_type(4)));   // MFMA acc

__device__ __forceinline__ unsigned f2bf(float f) {       // RNE pack
    unsigned u = __float_as_uint(f);
    return (u + 0x7fffu + ((u >> 16) & 1u)) >> 16;
}
__device__ __forceinline__ float bf2f_lo(unsigned u) { return __uint_as_float(u << 16); }
__device__ __forceinline__ float bf2f_hi(unsigned u) { return __uint_as_float(u & 0xffff0000u); }

// ================= fused prep: cast x -> bf16 | transpose W -> bf16 | deg=0 =================
__global__ __launch_bounds__(256) void k_prep(const float4* __restrict__ x4, uint2* __restrict__ xb,
                                              const float* __restrict__ W1, const float* __restrict__ W2,
                                              const float* __restrict__ Wmu, const float* __restrict__ Wlv,
                                              unsigned short* __restrict__ Wt, int* __restrict__ deg) {
    int b = blockIdx.x;
    if (b < 6250) {
        int i = b * 256 + threadIdx.x;
        if (i >= NN * 32) return;
        float4 v = x4[i];
        uint2 p;
        p.x = (f2bf(v.y) << 16) | f2bf(v.x);
        p.y = (f2bf(v.w) << 16) | f2bf(v.z);
        xb[i] = p;
    } else if (b < 6442) {
        int idx = (b - 6250) * 256 + threadIdx.x;
        if (idx >= 3 * 16384) return;
        int m = idx >> 14, i = idx & 16383;
        int n = i & 127, k = i >> 7;
        float v;
        if (m == 0)      v = W1[k * 128 + n];
        else if (m == 1) v = W2[k * 128 + n];
        else             v = (n < 64) ? Wmu[k * 64 + n] : Wlv[k * 64 + (n - 64)];
        Wt[m * 16384 + n * 128 + k] = (unsigned short)f2bf(v);
    } else {
        int i = (b - 6442) * 256 + threadIdx.x;
        if (i < NN) deg[i] = 0;
    }
}

// XCD-sliced degree count (block b&7 -> node slice, atomic targets stay in one L2)
__global__ __launch_bounds__(256) void k_deg_count(const int* __restrict__ dst, int* __restrict__ deg) {
    int xcd = blockIdx.x & 7;
    int e = (blockIdx.x >> 3) * 256 + threadIdx.x;
    if (e >= NE) return;
    int d = dst[e];
    if (d / NSLICE == xcd) atomicAdd(&deg[d], 1);
}

// ================= hierarchical scan (3 wide dispatches; single-block version was 164us) =================
// scan pass 1: per-block sums (+ fused dinv)
__global__ __launch_bounds__(256) void k_scan1(const int* __restrict__ deg, int* __restrict__ bsum,
                                               float* __restrict__ dinv) {
    __shared__ int s[256];
    int tid = threadIdx.x;
    int i = blockIdx.x * 256 + tid;
    int v = (i < NN) ? deg[i] : 0;
    s[tid] = v;
    if (i < NN) dinv[i] = rsqrtf((float)(v + 1));   // +1 = self loop
    __syncthreads();
    for (int d = 128; d > 0; d >>= 1) {
        if (tid < d) s[tid] += s[tid + d];
        __syncthreads();
    }
    if (tid == 0) bsum[blockIdx.x] = s[0];
}

// scan pass 2: exclusive scan of 196 block sums (single block, tiny)
__global__ __launch_bounds__(256) void k_scan2(int* bsum, int nblocks) {
    __shared__ int s[256];
    int tid = threadIdx.x;
    int v = (tid < nblocks) ? bsum[tid] : 0;
    s[tid] = v;
    __syncthreads();
    for (int d = 1; d < 256; d <<= 1) {
        int t = (tid >= d) ? s[tid - d] : 0;
        __syncthreads();
        s[tid] += t;
        __syncthreads();
    }
    if (tid < nblocks) bsum[tid] = s[tid] - v;   // exclusive
}

// scan pass 3: block-local exclusive scan + block offset -> off[] and cursor
__global__ __launch_bounds__(256) void k_scan3(int* __restrict__ deg, const int* __restrict__ bsum,
                                               int* __restrict__ off) {
    __shared__ int s[256];
    int tid = threadIdx.x;
    int i = blockIdx.x * 256 + tid;
    int v = (i < NN) ? deg[i] : 0;
    s[tid] = v;
    __syncthreads();
    for (int d = 1; d < 256; d <<= 1) {
        int t = (tid >= d) ? s[tid - d] : 0;
        __syncthreads();
        s[tid] += t;
        __syncthreads();
    }
    int excl = bsum[blockIdx.x] + s[tid] - v;
    if (i < NN) { off[i] = excl; deg[i] = excl; }   // deg becomes cursor
    if (i == 0) off[NN] = NE;
}

// XCD-sliced CSR fill (slice's ~800KB epair region stays in its XCD's L2)
__global__ __launch_bounds__(256) void k_fill(const int* __restrict__ src, const int* __restrict__ dst,
                                              const float* __restrict__ dinv,
                                              int* __restrict__ cursor, int2* __restrict__ epair) {
    int xcd = blockIdx.x & 7;
    int e = (blockIdx.x >> 3) * 256 + threadIdx.x;
    if (e >= NE) return;
    int d = dst[e];
    if (d / NSLICE != xcd) return;
    int s = src[e];
    int p = atomicAdd(&cursor[d], 1);
    epair[p] = make_int2(s, __float_as_int(dinv[s] * dinv[d]));
}

// ================= bf16 MFMA GEMM: Cb[N,128] = Xb[N,128] @ Wt^T =================
__global__ __launch_bounds__(256) void k_gemm(const unsigned short* __restrict__ Xb,
                                              const unsigned short* __restrict__ Wt,
                                              unsigned short* __restrict__ Cb, int N) {
    int wave = threadIdx.x >> 6, lane = threadIdx.x & 63;
    int quad = lane >> 4, l16 = lane & 15;
    int row0 = blockIdx.x * 64 + wave * 16;
    int arow = row0 + l16;
    int arc  = arow < N ? arow : N - 1;          // clamp (stores guarded)

    const s8v* xp = (const s8v*)(Xb + (size_t)arc * 128);
    s8v a0 = xp[quad], a1 = xp[4 + quad], a2 = xp[8 + quad], a3 = xp[12 + quad];

    f4v acc[8];
#pragma unroll
    for (int c = 0; c < 8; ++c) acc[c] = (f4v)0.f;

#pragma unroll
    for (int c = 0; c < 8; ++c) {
        const s8v* wp = (const s8v*)(Wt + (size_t)(c * 16 + l16) * 128);
        acc[c] = __builtin_amdgcn_mfma_f32_16x16x32_bf16(a0, wp[quad],      acc[c], 0, 0, 0);
        acc[c] = __builtin_amdgcn_mfma_f32_16x16x32_bf16(a1, wp[4 + quad],  acc[c], 0, 0, 0);
        acc[c] = __builtin_amdgcn_mfma_f32_16x16x32_bf16(a2, wp[8 + quad],  acc[c], 0, 0, 0);
        acc[c] = __builtin_amdgcn_mfma_f32_16x16x32_bf16(a3, wp[12 + quad], acc[c], 0, 0, 0);
    }

#pragma unroll
    for (int c = 0; c < 8; ++c) {
#pragma unroll
        for (int r = 0; r < 4; ++r) {
            int ro = row0 + quad * 4 + r;
            if (ro < N) Cb[(size_t)ro * 128 + c * 16 + l16] = (unsigned short)f2bf(acc[c][r]);
        }
    }
}

// ================= final: [mu|lv] = Xb @ Wt^T + bias, fp32 packed out =================
__global__ __launch_bounds__(256) void k_final(const unsigned short* __restrict__ Xb,
                                               const unsigned short* __restrict__ Wt,
                                               const float* __restrict__ bmu, const float* __restrict__ blv,
                                               float* __restrict__ out, int N) {
    int wave = threadIdx.x >> 6, lane = threadIdx.x & 63;
    int quad = lane >> 4, l16 = lane & 15;
    int row0 = blockIdx.x * 64 + wave * 16;
    int arow = row0 + l16;
    int arc  = arow < N ? arow : N - 1;

    const s8v* xp = (const s8v*)(Xb + (size_t)arc * 128);
    s8v a0 = xp[quad], a1 = xp[4 + quad], a2 = xp[8 + quad], a3 = xp[12 + quad];

    f4v acc[8];
#pragma unroll
    for (int c = 0; c < 8; ++c) acc[c] = (f4v)0.f;

#pragma unroll
    for (int c = 0; c < 8; ++c) {
        const s8v* wp = (const s8v*)(Wt + (size_t)(c * 16 + l16) * 128);
        acc[c] = __builtin_amdgcn_mfma_f32_16x16x32_bf16(a0, wp[quad],      acc[c], 0, 0, 0);
        acc[c] = __builtin_amdgcn_mfma_f32_16x16x32_bf16(a1, wp[4 + quad],  acc[c], 0, 0, 0);
        acc[c] = __builtin_amdgcn_mfma_f32_16x16x32_bf16(a2, wp[8 + quad],  acc[c], 0, 0, 0);
        acc[c] = __builtin_amdgcn_mfma_f32_16x16x32_bf16(a3, wp[12 + quad], acc[c], 0, 0, 0);
    }

#pragma unroll
    for (int c = 0; c < 8; ++c) {
        int col  = c * 16 + l16;
        float bb = (col < 64) ? bmu[col] : blv[col - 64];
#pragma unroll
        for (int r = 0; r < 4; ++r) {
            int ro = row0 + quad * 4 + r;
            if (ro < N) {
                float v = acc[c][r] + bb;
                if (col < 64) out[(size_t)ro * 64 + col] = v;
                else          out[(size_t)NN * 64 + (size_t)ro * 64 + (col - 64)] = v;
            }
        }
    }
}

// ================= gather agg (bf16) + self-loop + bias + relu -> bf16 =================
// 1 wave/node. Lane-group g=lane>>4 handles edge e0+g; lane loads dwordx4 (16B)
// at dword offset q*4 of its group's source row -> one instruction fetches 4
// whole rows (1KB). Butterfly-reduce subgroups; g==0 stores uint4.
__global__ __launch_bounds__(256) void k_agg(const unsigned short* __restrict__ hb, const int* __restrict__ off,
                                             const int2* __restrict__ epair, const float* __restrict__ dinv,
                                             const float* __restrict__ b, unsigned* __restrict__ outw) {
    int lane = threadIdx.x & 63;
    int g = lane >> 4, q = lane & 15;
    int n = blockIdx.x * 4 + (threadIdx.x >> 6);   // grid = 12500 -> n < 50000
    int o0 = __builtin_amdgcn_readfirstlane(off[n]);
    int o1 = __builtin_amdgcn_readfirstlane(off[n + 1]);

    float al0 = 0.f, al1 = 0.f, al2 = 0.f, al3 = 0.f;
    float ah0 = 0.f, ah1 = 0.f, ah2 = 0.f, ah3 = 0.f;

#define BATCH4_LOAD(e0, uj, wj)                                                          \
    {                                                                                    \
        int _i0 = ((e0) + 0 < o1) ? (e0) + 0 : 0;                                        \
        int _i1 = ((e0) + 1 < o1) ? (e0) + 1 : 0;                                        \
        int _i2 = ((e0) + 2 < o1) ? (e0) + 2 : 0;                                        \
        int _i3 = ((e0) + 3 < o1) ? (e0) + 3 : 0;                                        \
        int _s0 = __builtin_amdgcn_readfirstlane(epair[_i0].x);                          \
        int _s1 = __builtin_amdgcn_readfirstlane(epair[_i1].x);                          \
        int _s2 = __builtin_amdgcn_readfirstlane(epair[_i2].x);                          \
        int _s3 = __builtin_amdgcn_readfirstlane(epair[_i3].x);                          \
        float _w0 = ((e0) + 0 < o1) ? __int_as_float(__builtin_amdgcn_readfirstlane(epair[_i0].y)) : 0.f; \
        float _w1 = ((e0) + 1 < o1) ? __int_as_float(__builtin_amdgcn_readfirstlane(epair[_i1].y)) : 0.f; \
        float _w2 = ((e0) + 2 < o1) ? __int_as_float(__builtin_amdgcn_readfirstlane(epair[_i2].y)) : 0.f; \
        float _w3 = ((e0) + 3 < o1) ? __int_as_float(__builtin_amdgcn_readfirstlane(epair[_i3].y)) : 0.f; \
        int _ss = (g == 0) ? _s0 : (g == 1) ? _s1 : (g == 2) ? _s2 : _s3;                \
        wj = (g == 0) ? _w0 : (g == 1) ? _w1 : (g == 2) ? _w2 : _w3;                     \
        uj = ((const uint4*)(hb + (size_t)_ss * 128))[q];                                \
    }

#define BATCH4_FMA(uj, wj)                                                               \
    {                                                                                    \
        al0 += bf2f_lo(uj.x) * wj; ah0 += bf2f_hi(uj.x) * wj;                            \
        al1 += bf2f_lo(uj.y) * wj; ah1 += bf2f_hi(uj.y) * wj;                            \
        al2 += bf2f_lo(uj.z) * wj; ah2 += bf2f_hi(uj.z) * wj;                            \
        al3 += bf2f_lo(uj.w) * wj; ah3 += bf2f_hi(uj.w) * wj;                            \
    }

    {   // prologue: 24 edges, 6 independent 1KB gathers in flight
        uint4 u0, u1, u2, u3, u4, u5;
        float w0, w1, w2, w3, w4, w5;
        BATCH4_LOAD(o0 + 0,  u0, w0);
        BATCH4_LOAD(o0 + 4,  u1, w1);
        BATCH4_LOAD(o0 + 8,  u2, w2);
        BATCH4_LOAD(o0 + 12, u3, w3);
        BATCH4_LOAD(o0 + 16, u4, w4);
        BATCH4_LOAD(o0 + 20, u5, w5);
        BATCH4_FMA(u0, w0); BATCH4_FMA(u1, w1); BATCH4_FMA(u2, w2);
        BATCH4_FMA(u3, w3); BATCH4_FMA(u4, w4); BATCH4_FMA(u5, w5);
    }

    // epilogue for deg > 24 (P ~ 2%): masked 4-edge batches, 2 in flight
    for (int e0 = o0 + 24; e0 < o1; e0 += 8) {
        uint4 u0, u1; float w0, w1;
        BATCH4_LOAD(e0, u0, w0);
        BATCH4_LOAD(e0 + 4, u1, w1);
        BATCH4_FMA(u0, w0);
        BATCH4_FMA(u1, w1);
    }
#undef BATCH4_LOAD
#undef BATCH4_FMA

    // butterfly-reduce the 4 edge-subgroups (lanes differing in bits 4,5)
    al0 += __shfl_xor(al0, 16, 64); al0 += __shfl_xor(al0, 32, 64);
    ah0 += __shfl_xor(ah0, 16, 64); ah0 += __shfl_xor(ah0, 32, 64);
    al1 += __shfl_xor(al1, 16, 64); al1 += __shfl_xor(al1, 32, 64);
    ah1 += __shfl_xor(ah1, 16, 64); ah1 += __shfl_xor(ah1, 32, 64);
    al2 += __shfl_xor(al2, 16, 64); al2 += __shfl_xor(al2, 32, 64);
    ah2 += __shfl_xor(ah2, 16, 64); ah2 += __shfl_xor(ah2, 32, 64);
    al3 += __shfl_xor(al3, 16, 64); al3 += __shfl_xor(al3, 32, 64);
    ah3 += __shfl_xor(ah3, 16, 64); ah3 += __shfl_xor(ah3, 32, 64);

    if (g == 0) {
        float dn = dinv[n];
        float sn = dn * dn;
        uint4 uh = ((const uint4*)(hb + (size_t)n * 128))[q];
        const float2* b2 = (const float2*)b;
        float2 bb0 = b2[q * 4 + 0], bb1 = b2[q * 4 + 1];
        float2 bb2 = b2[q * 4 + 2], bb3 = b2[q * 4 + 3];
        uint4 o;
        float rx, ry;
        rx = fmaxf(al0 + bf2f_lo(uh.x) * sn + bb0.x, 0.f);
        ry = fmaxf(ah0 + bf2f_hi(uh.x) * sn + bb0.y, 0.f);
        o.x = (f2bf(ry) << 16) | f2bf(rx);
        rx = fmaxf(al1 + bf2f_lo(uh.y) * sn + bb1.x, 0.f);
        ry = fmaxf(ah1 + bf2f_hi(uh.y) * sn + bb1.y, 0.f);
        o.y = (f2bf(ry) << 16) | f2bf(rx);
        rx = fmaxf(al2 + bf2f_lo(uh.z) * sn + bb2.x, 0.f);
        ry = fmaxf(ah2 + bf2f_hi(uh.z) * sn + bb2.y, 0.f);
        o.z = (f2bf(ry) << 16) | f2bf(rx);
        rx = fmaxf(al3 + bf2f_lo(uh.w) * sn + bb3.x, 0.f);
        ry = fmaxf(ah3 + bf2f_hi(uh.w) * sn + bb3.y, 0.f);
        o.w = (f2bf(ry) << 16) | f2bf(rx);
        ((uint4*)(outw + (size_t)n * 64))[q] = o;
    }
}

extern "C" void kernel_launch(void* const* d_in, const int* in_sizes, int n_in,
                              void* d_out, int out_size, void* d_ws, size_t ws_size,
                              hipStream_t stream) {
    const float* x    = (const float*)d_in[0];
    const int*   eidx = (const int*)d_in[1];
    const float* W1   = (const float*)d_in[2];
    const float* b1   = (const float*)d_in[3];
    const float* W2   = (const float*)d_in[4];
    const float* b2   = (const float*)d_in[5];
    const float* Wmu  = (const float*)d_in[6];
    const float* bmu  = (const float*)d_in[7];
    const float* Wlv  = (const float*)d_in[8];
    const float* blv  = (const float*)d_in[9];
    float* out = (float*)d_out;

    const int* src = eidx;        // edge_index[0]
    const int* dst = eidx + NE;   // edge_index[1]

    // workspace layout (4-byte units)
    float*          ws    = (float*)d_ws;
    float*          dinv  = ws;                            // 50048
    int*            deg   = (int*)(ws + 50048);            // 50048 (becomes cursor)
    int*            off   = (int*)(ws + 100096);           // 50048
    int*            bsum  = (int*)(ws + 150144);           // 256
    int2*           epair = (int2*)(ws + 150400);          // 800000 int2
    unsigned short* Wt    = (unsigned short*)(ws + 1750400);   // 3*16384 bf16
    unsigned short* Xb    = (unsigned short*)(ws + 1775000);   // 6.4M bf16
    unsigned short* Hb    = (unsigned short*)(ws + 4975000);   // 6.4M bf16
    unsigned short* Gb    = (unsigned short*)(ws + 8175000);   // 6.4M bf16

    const int gN  = (NN + 255) / 256;        // 196
    const int gE8 = ((NE + 255) / 256) * 8;  // 25000 (XCD-sliced passes)
    const int gG  = (NN + 63) / 64;          // 782
    const int gA  = NN / 4;                  // 12500
    const int gP  = 6250 + 192 + 196;        // fused prep grid

    // ---- fused prep: cast x, transpose W, zero deg ----
    k_prep<<<gP, 256, 0, stream>>>((const float4*)x, (uint2*)Xb, W1, W2, Wmu, Wlv, Wt, deg);

    // ---- CSR build + norms ----
    k_deg_count<<<gE8, 256, 0, stream>>>(dst, deg);
    k_scan1<<<gN, 256, 0, stream>>>(deg, bsum, dinv);
    k_scan2<<<1, 256, 0, stream>>>(bsum, gN);
    k_scan3<<<gN, 256, 0, stream>>>(deg, bsum, off);
    k_fill<<<gE8, 256, 0, stream>>>(src, dst, dinv, deg, epair);

    // ---- conv1: Hb = Xb@W1 ; Gb = relu(agg(Hb) + self + b1) ----
    k_gemm<<<gG, 256, 0, stream>>>(Xb, Wt, Hb, NN);
    k_agg<<<gA, 256, 0, stream>>>(Hb, off, epair, dinv, b1, (unsigned*)Gb);

    // ---- conv2: Hb = Gb@W2 ; Gb = relu(agg(Hb) + self + b2) ----
    k_gemm<<<gG, 256, 0, stream>>>(Gb, Wt + 16384, Hb, NN);
    k_agg<<<gA, 256, 0, stream>>>(Hb, off, epair, dinv, b2, (unsigned*)Gb);

    // ---- final projection ----
    k_final<<<gG, 256, 0, stream>>>(Gb, Wt + 32768, bmu, blv, out, NN);
}